// Round 3
// baseline (318.936 us; speedup 1.0000x reference)
//
#include <hip/hip_runtime.h>
#include <math.h>

// Problem constants (fixed shapes per setup_inputs):
//   x_in: (32768, 543, 3) fp32; num_frames=16384; segments=4; input_shape=(16384,240)
//   out = [5 stat feats of 480] + [16384*240 pair-averaged] = 3934560 fp32
//
// Bilinear 2:1 resize (half-pixel, antialias=False) == out[i] = 0.5*(x[2i]+x[2i+1]).
// rem = 32768 % 4 == 0 -> reference applies NO symmetric padding; segments are
// exactly 4 x 8192 frames.
#define T_FRAMES   32768
#define FRAME      1629              // 543*3 floats per frame
#define FPB        16                // frames per block
#define NBLOCKS    (T_FRAMES / FPB)  // 2048  (up to 8 blocks/CU resident)
#define OUT_B_OFF  2400              // 5 feats * 480
#define SEG_BLOCKS (NBLOCKS / 4)     // 512 blocks per segment
#define MID_OFF    ((size_t)NBLOCKS * 480)  // float offset of mid[16][480] in ws

__constant__ int c_astart[10] = {0, 40, 80, 140, 200, 260, 320, 370, 420, 480};
__constant__ int c_alen[10]   = {40, 40, 60, 60, 60, 60, 50, 50, 60, 63};

// One block = 16 consecutive frames = 8 output rows, all inside one segment.
// Stage unit = 2 frames (3258 floats = 1629 float2, 8B-aligned) -> 13 KB LDS,
// letting 8 blocks/CU co-reside (32 waves/CU) to hide HBM latency via TLP.
__global__ __launch_bounds__(256) void featgen_main(
    const float* __restrict__ xin, float* __restrict__ out, float* __restrict__ part)
{
    __shared__ float rows[2 * FRAME];   // 13032 B: 2 staged frames
    __shared__ float xavg[2 * 32];      // 2 frames x 30 range-means (padded)

    const int t = threadIdx.x;
    const int b = blockIdx.x;
    const float* src = xin + (size_t)b * (FPB * FRAME);

    // Phase-A role: 8 lanes per (landmark-range, channel); groups stay in-wave.
    const int g8 = t >> 3;   // 0..31, active if < 30
    const int j8 = t & 7;
    int a_s = 0, a_n = 0, a_c = 0;
    float a_inv = 0.0f;
    if (g8 < 30) {
        int l = g8 / 3; a_c = g8 - 3 * l;
        a_s = c_astart[l]; a_n = c_alen[l];
        a_inv = 1.0f / (float)a_n;
    }

    float ssum = 0.0f, ssq = 0.0f;   // thread t owns feature k=t (t<240)

    for (int u = 0; u < 8; ++u) {
        // ---- stage 2 frames: 1629 float2, coalesced ----
        const float2* s2 = (const float2*)(src + u * (2 * FRAME));
        float2* d2 = (float2*)rows;
        #pragma unroll
        for (int i = 0; i < 7; ++i) {
            int idx = t + i * 256;
            if (idx < FRAME) d2[idx] = s2[idx];
        }
        __syncthreads();

        // ---- phase A: cooperative range-means (8 lanes each, shfl reduce) ----
        if (g8 < 30) {
            #pragma unroll
            for (int f = 0; f < 2; ++f) {
                const float* row = rows + f * FRAME;
                float s = 0.0f;
                for (int j = j8; j < a_n; j += 8) s += row[(a_s + j) * 3 + a_c];
                s += __shfl_xor(s, 1, 8);
                s += __shfl_xor(s, 2, 8);
                s += __shfl_xor(s, 4, 8);
                if (j8 == 0) xavg[f * 32 + g8] = s * a_inv;
            }
        }
        __syncthreads();

        // ---- phase B: pair-averaged output row + stats accumulation ----
        if (t < 240) {
            float v0, v1;
            if (t < 30) {
                v0 = xavg[t]; v1 = xavg[32 + t];
            } else {
                // point landmark 468+(l-10): frame offset = t + 468*3 - 30 = t+1374
                v0 = rows[t + 1374];
                v1 = rows[FRAME + t + 1374];
            }
            out[OUT_B_OFF + ((size_t)b * 8 + u) * 240 + t] = 0.5f * (v0 + v1);
            ssum += v0 + v1;
            ssq  += v0 * v0 + v1 * v1;
        }
        __syncthreads();   // protect rows before next stage overwrites
    }

    // Deterministic per-block partials (no atomics, no zero-init kernel).
    if (t < 240) {
        part[(size_t)b * 480 + t]       = ssum;
        part[(size_t)b * 480 + 240 + t] = ssq;
    }
}

// Level-1 reduce: 16 blocks = (seg f, chunk c); each sums 128 block-partials.
// NOTE: launched with 512 threads -> launch_bounds MUST be >= 512 (R2 bug).
__global__ __launch_bounds__(512) void reduce_parts(
    const float* __restrict__ part, float* __restrict__ mid)
{
    const int f = blockIdx.x >> 2;
    const int c = blockIdx.x & 3;
    const int t = threadIdx.x;
    if (t >= 480) return;
    const int b0 = f * SEG_BLOCKS + c * (SEG_BLOCKS / 4);
    float s = 0.0f;
    #pragma unroll 4
    for (int b = 0; b < SEG_BLOCKS / 4; ++b)
        s += part[(size_t)(b0 + b) * 480 + t];
    mid[(size_t)blockIdx.x * 480 + t] = s;
}

// Level-2: 5 blocks -> mean/std. f<4 sums 4 chunks of its segment; f=4 sums all 16.
__global__ __launch_bounds__(256) void finalize_stats(
    const float* __restrict__ mid, float* __restrict__ out)
{
    const int f = blockIdx.x;
    const int t = threadIdx.x;
    if (t >= 240) return;
    float s = 0.0f, q = 0.0f, n;
    if (f < 4) {
        #pragma unroll
        for (int c = 0; c < 4; ++c) {
            s += mid[(size_t)(f * 4 + c) * 480 + t];
            q += mid[(size_t)(f * 4 + c) * 480 + 240 + t];
        }
        n = 8192.0f;
    } else {
        #pragma unroll
        for (int m = 0; m < 16; ++m) {
            s += mid[(size_t)m * 480 + t];
            q += mid[(size_t)m * 480 + 240 + t];
        }
        n = 32768.0f;
    }
    float mean = s / n;
    float var  = q / n - mean * mean;
    var = var < 0.0f ? 0.0f : var;
    out[f * 480 + t]       = mean;
    out[f * 480 + 240 + t] = sqrtf(var);
}

extern "C" void kernel_launch(void* const* d_in, const int* in_sizes, int n_in,
                              void* d_out, int out_size, void* d_ws, size_t ws_size,
                              hipStream_t stream) {
    (void)in_sizes; (void)n_in; (void)out_size; (void)ws_size;
    const float* xin = (const float*)d_in[0];
    float* out  = (float*)d_out;
    float* part = (float*)d_ws;
    float* mid  = part + MID_OFF;

    featgen_main<<<NBLOCKS, 256, 0, stream>>>(xin, out, part);
    reduce_parts<<<16, 512, 0, stream>>>(part, mid);
    finalize_stats<<<5, 256, 0, stream>>>(mid, out);
}

// Round 4
// 311.485 us; speedup vs baseline: 1.0239x; 1.0239x over previous
//
#include <hip/hip_runtime.h>
#include <math.h>

// Problem constants (fixed shapes per setup_inputs):
//   x_in: (32768, 543, 3) fp32; num_frames=16384; segments=4; input_shape=(16384,240)
//   out = [5 stat feats of 480] + [16384*240 pair-averaged] = 3934560 fp32
//
// Bilinear 2:1 resize (half-pixel, antialias=False) == out[i] = 0.5*(x[2i]+x[2i+1]).
// rem = 32768 % 4 == 0 -> reference applies NO symmetric padding; segments are
// exactly 4 x 8192 frames.
#define T_FRAMES   32768
#define FRAME      1629              // 543*3 floats per frame
#define FPB        32                // frames per block
#define NBLOCKS    (T_FRAMES / FPB)  // 1024
#define OUT_B_OFF  2400              // 5 feats * 480
#define SEG_BLOCKS (NBLOCKS / 4)     // 256 blocks per segment
#define MID_OFF    ((size_t)NBLOCKS * 480)  // float offset of mid[16][480] in ws

__constant__ int c_astart[10] = {0, 40, 80, 140, 200, 260, 320, 370, 420, 480};
__constant__ int c_alen[10]   = {40, 40, 60, 60, 60, 60, 50, 50, 60, 63};

// One block = 32 consecutive frames = 16 output rows, all inside one segment.
// Stage unit = 4 frames (6516 floats = 1629 float4, 16B-aligned) -> 26 KB LDS,
// 6 blocks/CU resident; 16 B/lane staging is the coalescing sweet spot
// (R1 float4 variant measured ~10 us faster end-to-end than R3 float2).
__global__ __launch_bounds__(256) void featgen_main(
    const float* __restrict__ xin, float* __restrict__ out, float* __restrict__ part)
{
    __shared__ float rows[4 * FRAME];   // 26064 B: 4 staged frames
    __shared__ float xavg[4 * 32];      // 4 frames x 30 range-means (padded)

    const int t = threadIdx.x;
    const int b = blockIdx.x;
    const float* src = xin + (size_t)b * (FPB * FRAME);

    // Phase-A role: 8 lanes per (landmark-range, channel); groups stay in-wave.
    const int g8 = t >> 3;   // 0..31, active if < 30
    const int j8 = t & 7;
    int a_s = 0, a_n = 0, a_c = 0;
    float a_inv = 0.0f;
    if (g8 < 30) {
        int l = g8 / 3; a_c = g8 - 3 * l;
        a_s = c_astart[l]; a_n = c_alen[l];
        a_inv = 1.0f / (float)a_n;
    }

    float ssum = 0.0f, ssq = 0.0f;   // thread t owns feature k=t (t<240)

    for (int u = 0; u < 8; ++u) {
        // ---- stage 4 frames: 1629 float4, coalesced 16B/lane ----
        const float4* s4 = (const float4*)(src + u * (4 * FRAME));
        float4* d4 = (float4*)rows;
        #pragma unroll
        for (int i = 0; i < 7; ++i) {
            int idx = t + i * 256;
            if (idx < FRAME) d4[idx] = s4[idx];
        }
        __syncthreads();

        // ---- phase A: cooperative range-means (8 lanes each, shfl reduce) ----
        if (g8 < 30) {
            #pragma unroll
            for (int f = 0; f < 4; ++f) {
                const float* row = rows + f * FRAME;
                float s = 0.0f;
                for (int j = j8; j < a_n; j += 8) s += row[(a_s + j) * 3 + a_c];
                s += __shfl_xor(s, 1, 8);
                s += __shfl_xor(s, 2, 8);
                s += __shfl_xor(s, 4, 8);
                if (j8 == 0) xavg[f * 32 + g8] = s * a_inv;
            }
        }
        __syncthreads();

        // ---- phase B: two pair-averaged output rows + stats accumulation ----
        if (t < 240) {
            float v0, v1, v2, v3;
            if (t < 30) {
                v0 = xavg[t];      v1 = xavg[32 + t];
                v2 = xavg[64 + t]; v3 = xavg[96 + t];
            } else {
                // point landmark 468+(l-10): frame offset = t + 468*3 - 30 = t+1374
                v0 = rows[t + 1374];
                v1 = rows[FRAME + t + 1374];
                v2 = rows[2 * FRAME + t + 1374];
                v3 = rows[3 * FRAME + t + 1374];
            }
            const size_t row0 = (size_t)b * 16 + (size_t)u * 2;
            out[OUT_B_OFF + row0 * 240 + t]       = 0.5f * (v0 + v1);
            out[OUT_B_OFF + (row0 + 1) * 240 + t] = 0.5f * (v2 + v3);
            ssum += v0 + v1 + v2 + v3;
            ssq  += v0 * v0 + v1 * v1 + v2 * v2 + v3 * v3;
        }
        __syncthreads();   // protect rows before next stage overwrites
    }

    // Deterministic per-block partials (no atomics, no zero-init kernel).
    if (t < 240) {
        part[(size_t)b * 480 + t]       = ssum;
        part[(size_t)b * 480 + 240 + t] = ssq;
    }
}

// Level-1 reduce: 16 blocks = (seg f, chunk c); each sums 64 block-partials.
// Launched with 512 threads -> launch_bounds must be >= 512.
__global__ __launch_bounds__(512) void reduce_parts(
    const float* __restrict__ part, float* __restrict__ mid)
{
    const int f = blockIdx.x >> 2;
    const int c = blockIdx.x & 3;
    const int t = threadIdx.x;
    if (t >= 480) return;
    const int b0 = f * SEG_BLOCKS + c * (SEG_BLOCKS / 4);
    float s = 0.0f;
    #pragma unroll 4
    for (int b = 0; b < SEG_BLOCKS / 4; ++b)
        s += part[(size_t)(b0 + b) * 480 + t];
    mid[(size_t)blockIdx.x * 480 + t] = s;
}

// Level-2: 5 blocks -> mean/std. f<4 sums 4 chunks of its segment; f=4 sums all 16.
__global__ __launch_bounds__(256) void finalize_stats(
    const float* __restrict__ mid, float* __restrict__ out)
{
    const int f = blockIdx.x;
    const int t = threadIdx.x;
    if (t >= 240) return;
    float s = 0.0f, q = 0.0f, n;
    if (f < 4) {
        #pragma unroll
        for (int c = 0; c < 4; ++c) {
            s += mid[(size_t)(f * 4 + c) * 480 + t];
            q += mid[(size_t)(f * 4 + c) * 480 + 240 + t];
        }
        n = 8192.0f;
    } else {
        #pragma unroll
        for (int m = 0; m < 16; ++m) {
            s += mid[(size_t)m * 480 + t];
            q += mid[(size_t)m * 480 + 240 + t];
        }
        n = 32768.0f;
    }
    float mean = s / n;
    float var  = q / n - mean * mean;
    var = var < 0.0f ? 0.0f : var;
    out[f * 480 + t]       = mean;
    out[f * 480 + 240 + t] = sqrtf(var);
}

extern "C" void kernel_launch(void* const* d_in, const int* in_sizes, int n_in,
                              void* d_out, int out_size, void* d_ws, size_t ws_size,
                              hipStream_t stream) {
    (void)in_sizes; (void)n_in; (void)out_size; (void)ws_size;
    const float* xin = (const float*)d_in[0];
    float* out  = (float*)d_out;
    float* part = (float*)d_ws;
    float* mid  = part + MID_OFF;

    featgen_main<<<NBLOCKS, 256, 0, stream>>>(xin, out, part);
    reduce_parts<<<16, 512, 0, stream>>>(part, mid);
    finalize_stats<<<5, 256, 0, stream>>>(mid, out);
}